// Round 5
// baseline (391.901 us; speedup 1.0000x reference)
//
#include <hip/hip_runtime.h>
#include <hip/hip_bf16.h>
#include <math.h>

typedef __bf16 bf16_t;
typedef __bf16 bf8 __attribute__((ext_vector_type(8)));
typedef __bf16 bf4 __attribute__((ext_vector_type(4)));
typedef float f32x4 __attribute__((ext_vector_type(4)));
typedef int i32x8 __attribute__((ext_vector_type(8)));
typedef unsigned char u8;

#define AS1 __attribute__((address_space(1)))
#define AS3 __attribute__((address_space(3)))

#define B_ROWS 4096
#define NTOT   8192
#define DIN    1024
#define DENC   512
#define DH     256
#define DP     128
#define NSLICE 64
#define GRID   512
#define INV_T        14.285714285714286f   // 1/0.07
#define SCALE_LOG2   20.609929155556620f   // log2(e)/0.07

__device__ __forceinline__ f32x4 mfma_16x16x32(bf8 a, bf8 b, f32x4 c) {
  return __builtin_amdgcn_mfma_f32_16x16x32_bf16(a, b, c, 0, 0, 0);
}

// ---------------------------------------------------------------------------
// R16: ONE persistent kernel. R1-R4 showed total (182-192us) is insensitive
// to per-kernel work (~45-60us of real pipe work across 7 dispatches) —
// the dominant term is inter-dispatch overhead. Fuse everything; phases
// separated by hand-rolled device-scope grid barriers.
//   Residency proof (hang-safety): 512 blocks = 256 CU x 2 blocks/CU.
//   launch_bounds(256,2) caps VGPR<=256 (2 waves/SIMD possible); LDS
//   36864 B/block -> 2x = 73.7 KB <= 160 KB. All 512 blocks co-resident.
//   Cross-XCD visibility: each wave's stores drain at __syncthreads
//   (vmcnt(0)); thread0's agent-scope release fence flushes L2 (wbl2);
//   acquire fence after the spin invalidates (inv) before readers proceed.
// ---------------------------------------------------------------------------
__device__ __forceinline__ void grid_sync(unsigned* syncc, int slot) {
  __syncthreads();                         // drains this block's vmem/lds
  if (threadIdx.x == 0) {
    __builtin_amdgcn_fence(__ATOMIC_RELEASE, "agent");
    __hip_atomic_fetch_add(&syncc[slot * 16], 1u, __ATOMIC_RELAXED,
                           __HIP_MEMORY_SCOPE_AGENT);
    while (__hip_atomic_load(&syncc[slot * 16], __ATOMIC_RELAXED,
                             __HIP_MEMORY_SCOPE_AGENT) < (unsigned)GRID) {}
    __builtin_amdgcn_fence(__ATOMIC_ACQUIRE, "agent");
  }
  __syncthreads();
}

// ---- R4-verified counted-vmcnt GEMM tile (3-buf, s_barrier + vmcnt(S)) ----
template<int MT, bool RELU>
__device__ __forceinline__ void gemm_tile(
    const bf16_t* A, const bf16_t* Bt, const float* bias, bf16_t* outp,
    int N, int K, int nb, int mb, char* base) {
  const int tid  = threadIdx.x;
  const int wave = tid >> 6;
  const int lane = tid & 63;
  const int l15  = lane & 15;
  const int quad = lane >> 4;
  constexpr int CH  = MT / 64;
  constexpr int ASZ = MT * 32;             // elems per A buffer
  constexpr int BSZ = 64 * 32;
  bf16_t* As = (bf16_t*)base;              // 3 * ASZ elems
  bf16_t* Bs = (bf16_t*)(base + (size_t)3 * ASZ * 2);

  f32x4 acc[CH][4];
  #pragma unroll
  for (int i = 0; i < CH; ++i)
    #pragma unroll
    for (int j = 0; j < 4; ++j) acc[i][j] = (f32x4){0.f, 0.f, 0.f, 0.f};

  auto stage = [&](int k0, int pb) {
    #pragma unroll
    for (int i = 0; i < CH; ++i) {
      const int s = tid + i * 256;
      const bf16_t* ga = A + (size_t)(mb + (s >> 2)) * K + k0 + (s & 3) * 8;
      __builtin_amdgcn_global_load_lds(
          (const AS1 void*)ga,
          (AS3 void*)(As + (size_t)pb * ASZ + (size_t)(wave * 64 + i * 256) * 8),
          16, 0, 0);
    }
    const bf16_t* gb = Bt + (size_t)(nb + (tid >> 2)) * K + k0 + (tid & 3) * 8;
    __builtin_amdgcn_global_load_lds(
        (const AS1 void*)gb,
        (AS3 void*)(Bs + (size_t)pb * BSZ + (size_t)(wave * 64) * 8), 16, 0, 0);
  };

  const int T = K >> 5;
  stage(0, 0);
  stage(32, 1);
  for (int t = 0; t < T; ++t) {
    if (t == T - 1) {
      asm volatile("s_waitcnt vmcnt(0)" ::: "memory");
    } else {
      if constexpr (CH == 2) asm volatile("s_waitcnt vmcnt(3)" ::: "memory");
      else                   asm volatile("s_waitcnt vmcnt(2)" ::: "memory");
    }
    __builtin_amdgcn_s_barrier();
    if (t + 2 < T) stage((t + 2) << 5, (t + 2) % 3);
    const bf16_t* as = As + (size_t)(t % 3) * ASZ;
    const bf16_t* bs = Bs + (size_t)(t % 3) * BSZ;
    bf8 a[CH];
    #pragma unroll
    for (int i = 0; i < CH; ++i)
      a[i] = *(const bf8*)(as + (size_t)(wave * (16 * CH) + i * 16 + l15) * 32 + quad * 8);
    #pragma unroll
    for (int nt = 0; nt < 4; ++nt) {
      bf8 bb = *(const bf8*)(bs + (size_t)(nt * 16 + l15) * 32 + quad * 8);
      #pragma unroll
      for (int i = 0; i < CH; ++i)
        acc[i][nt] = mfma_16x16x32(a[i], bb, acc[i][nt]);
    }
  }

  #pragma unroll
  for (int i = 0; i < CH; ++i) {
    const int orow = mb + wave * (16 * CH) + i * 16 + quad * 4;
    #pragma unroll
    for (int nt = 0; nt < 4; ++nt) {
      const int ocol = nb + nt * 16 + l15;
      const float bval = bias[ocol];
      #pragma unroll
      for (int r = 0; r < 4; ++r) {
        float v = acc[i][nt][r] + bval;
        if (RELU) v = fmaxf(v, 0.f);
        outp[(size_t)(orow + r) * N + ocol] = (bf16_t)v;
      }
    }
  }
}

// ---------------------------------------------------------------------------
__global__ __launch_bounds__(256, 2) void fused_all(
    const float* x_i, const float* x_t,
    const float* We_i, const float* We_t,
    const float* W1_i, const float* W1_t,
    const float* W2_i, const float* W2_t,
    const float* be_i, const float* be_t,
    const float* b1_i, const float* b1_t,
    const float* b2_i, const float* b2_t,
    bf16_t* xb_i, bf16_t* xb_t,
    bf16_t* Wet_i, bf16_t* Wet_t,
    bf16_t* W1t_i, bf16_t* W1t_t,
    bf16_t* W2t_i, bf16_t* W2t_t,
    bf16_t* h_i, bf16_t* h_t,
    bf16_t* g_i, bf16_t* g_t,
    u8* reps8, float* Spart,
    float* partials, unsigned* syncc,
    float* out) {
  __shared__ __align__(16) char smem[36864];
  const int bid  = blockIdx.x;
  const int tid  = threadIdx.x;
  const int wave = tid >> 6;
  const int lane = tid & 63;
  const int l15  = lane & 15;
  const int quad = lane >> 4;

  // ===== phase 0: prep (weight transpose + x cast), grid-stride ===========
  for (int b = bid; b < 8528; b += GRID) {
    if (b >= 336) {                        // ---- cast path
      int idx = (b - 336) * 256 + tid;
      const int HALF = (B_ROWS * DIN) / 4;
      const float* s; bf16_t* d; int off;
      if (idx < HALF) { s = x_i; d = xb_i; off = idx; }
      else            { s = x_t; d = xb_t; off = idx - HALF; }
      float4 v = ((const float4*)s)[off];
      bf4 w = { (bf16_t)v.x, (bf16_t)v.y, (bf16_t)v.z, (bf16_t)v.w };
      ((bf4*)d)[off] = w;
    } else {                               // ---- transpose path (once/block)
      const float* src; bf16_t* dst; int K, N, tile;
      if (b < 128)      { src = We_i; dst = Wet_i; K = 1024; N = 512; tile = b; }
      else if (b < 256) { src = We_t; dst = Wet_t; K = 1024; N = 512; tile = b - 128; }
      else if (b < 288) { src = W1_i; dst = W1t_i; K = 512;  N = 256; tile = b - 256; }
      else if (b < 320) { src = W1_t; dst = W1t_t; K = 512;  N = 256; tile = b - 288; }
      else if (b < 328) { src = W2_i; dst = W2t_i; K = 256;  N = 128; tile = b - 320; }
      else              { src = W2_t; dst = W2t_t; K = 256;  N = 128; tile = b - 328; }
      const int tilesN = N >> 6;
      const int k0 = (tile / tilesN) * 64;
      const int n0 = (tile % tilesN) * 64;
      float (*ld)[65] = (float(*)[65])smem;    // 16640 B
      #pragma unroll
      for (int i = 0; i < 4; ++i) {
        int cid = tid + i * 256;
        int r = cid >> 4;
        int c = (cid & 15) * 4;
        float4 v = *(const float4*)(src + (size_t)(k0 + r) * N + n0 + c);
        ld[r][c + 0] = v.x; ld[r][c + 1] = v.y; ld[r][c + 2] = v.z; ld[r][c + 3] = v.w;
      }
      __syncthreads();
      #pragma unroll
      for (int i = 0; i < 2; ++i) {
        int cid = tid + i * 256;
        int rn = cid >> 3;
        int c8 = (cid & 7) * 8;
        bf8 w;
        #pragma unroll
        for (int j = 0; j < 8; ++j) w[j] = (bf16_t)ld[c8 + j][rn];
        *(bf8*)(dst + (size_t)(n0 + rn) * K + k0 + c8) = w;
      }
    }
  }
  grid_sync(syncc, 0);

  // ===== phase 1: encoder h = x @ We + be  (512 tiles, 1:1) ===============
  {
    const int nbi = bid & 7, mbi = (bid >> 3) & 31, z = bid >> 8;
    gemm_tile<128, false>(z ? xb_t : xb_i, z ? Wet_t : Wet_i,
                          z ? be_t : be_i, z ? h_t : h_i,
                          DENC, DIN, nbi * 64, mbi * 128, smem);
  }
  grid_sync(syncc, 1);

  // ===== phase 2: head1 g = relu(h @ W1 + b1)  (512 tiles, 1:1) ===========
  {
    const int nbi = bid & 3, mbi = (bid >> 2) & 63, z = bid >> 8;
    gemm_tile<64, true>(z ? h_t : h_i, z ? W1t_t : W1t_i,
                        z ? b1_t : b1_i, z ? g_t : g_i,
                        DH, DENC, nbi * 64, mbi * 64, smem);
  }
  grid_sync(syncc, 2);

  // ===== phase 3: head2 + L2-norm -> fp8 reps8  (512 tiles, 1:1) ==========
  {
    const int z = bid >> 8;
    const int mb = (bid & 255) * 16;
    const bf16_t* A    = z ? g_t : g_i;
    const bf16_t* Bt   = z ? W2t_t : W2t_i;
    const float*  bias = z ? b2_t : b2_i;
    bf16_t* Asb = (bf16_t*)smem;                     // 2 x 512 elems (2 KB)
    bf16_t* Bsb = (bf16_t*)(smem + 2048);            // 2 x 4096 elems (16 KB)
    float*  ssL = (float*)(smem + 2048 + 16384);     // 64 floats
    const int wc0 = wave * 32;

    f32x4 acc2[2];
    acc2[0] = (f32x4){0.f, 0.f, 0.f, 0.f};
    acc2[1] = (f32x4){0.f, 0.f, 0.f, 0.f};

    auto stageh = [&](int k0, int pb) {
      if (wave == 0) {                     // A: 64 slots of 16B
        const int row = lane >> 2, j = lane & 3, cf = j ^ (row & 3);
        const bf16_t* ga = A + (size_t)(mb + row) * DH + k0 + cf * 8;
        __builtin_amdgcn_global_load_lds(
            (const AS1 void*)ga, (AS3 void*)(Asb + (size_t)pb * 512), 16, 0, 0);
      }
      #pragma unroll
      for (int i = 0; i < 2; ++i) {        // B: 512 slots of 16B
        const int s = wave * 64 + i * 256 + lane;
        const int col = s >> 2, j = s & 3, cf = j ^ (col & 3);
        const bf16_t* gb = Bt + (size_t)col * DH + k0 + cf * 8;
        __builtin_amdgcn_global_load_lds(
            (const AS1 void*)gb,
            (AS3 void*)(Bsb + (size_t)pb * 4096 + (size_t)(wave * 64 + i * 256) * 8),
            16, 0, 0);
      }
    };

    stageh(0, 0);
    for (int t = 0; t < 8; ++t) {
      __syncthreads();
      if (t < 7) stageh((t + 1) << 5, (t + 1) & 1);
      const bf16_t* as = Asb + (size_t)(t & 1) * 512;
      const bf16_t* bs = Bsb + (size_t)(t & 1) * 4096;
      bf8 a = *(const bf8*)(as + (size_t)(l15 * 4 + (quad ^ (l15 & 3))) * 8);
      #pragma unroll
      for (int nt = 0; nt < 2; ++nt) {
        const int col = wc0 + nt * 16 + l15;
        bf8 bb = *(const bf8*)(bs + (size_t)(col * 4 + (quad ^ (col & 3))) * 8);
        acc2[nt] = mfma_16x16x32(a, bb, acc2[nt]);
      }
    }

    float ssp[4];
    #pragma unroll
    for (int r = 0; r < 4; ++r) {
      #pragma unroll
      for (int nt = 0; nt < 2; ++nt) acc2[nt][r] += bias[wc0 + nt * 16 + l15];
      float s = acc2[0][r] * acc2[0][r] + acc2[1][r] * acc2[1][r];
      s += __shfl_xor(s, 1); s += __shfl_xor(s, 2);
      s += __shfl_xor(s, 4); s += __shfl_xor(s, 8);
      ssp[r] = s;
    }
    if (l15 == 0) {
      #pragma unroll
      for (int r = 0; r < 4; ++r) ssL[wave * 16 + quad * 4 + r] = ssp[r];
    }
    __syncthreads();
    const size_t gr0 = (size_t)(z ? B_ROWS : 0) + mb + quad * 4;
    #pragma unroll
    for (int r = 0; r < 4; ++r) {
      const int row = quad * 4 + r;
      float tot = ssL[row] + ssL[16 + row] + ssL[32 + row] + ssL[48 + row];
      const float inv = 1.0f / fmaxf(sqrtf(tot), 1e-12f);
      int pk = __builtin_amdgcn_cvt_pk_fp8_f32(acc2[0][r] * inv, acc2[1][r] * inv, 0, 0);
      reps8[(gr0 + r) * DP + wc0 + l15]      = (u8)(pk & 0xff);
      reps8[(gr0 + r) * DP + wc0 + 16 + l15] = (u8)((pk >> 8) & 0xff);
    }
  }
  grid_sync(syncc, 3);

  // ===== phase 4: sim partials (1056 tri-tiles, grid-stride) ==============
  for (int ll = bid; ll < 1056; ll += GRID) {
    int by = (int)((65.0f - sqrtf(4225.0f - 4.0f * (float)ll)) * 0.5f);
    while ((by + 1) * (65 - (by + 1)) <= ll) ++by;
    while (by * (65 - by) > ll) --by;
    const int bxh = 2 * by + (ll - by * (65 - by));
    const bool diag = (bxh - 2 * by) < 2;
    const int rowbase = by * 256;
    const int col0    = bxh * 128;

    u8*    Bs8 = (u8*)smem;                // 2 x 8 KB
    float* csw = (float*)(smem + 16384);   // [4][128]

    const int r0 = rowbase + wave * 64;
    i32x8 af[4];
    #pragma unroll
    for (int c = 0; c < 4; ++c) {
      const uint4* ap = (const uint4*)(reps8 + (size_t)(r0 + c * 16 + l15) * DP + quad * 32);
      uint4 x0 = ap[0], x1 = ap[1];
      af[c] = (i32x8){(int)x0.x, (int)x0.y, (int)x0.z, (int)x0.w,
                      (int)x1.x, (int)x1.y, (int)x1.z, (int)x1.w};
    }

    float rs[4][4];
    #pragma unroll
    for (int c = 0; c < 4; ++c)
      #pragma unroll
      for (int r = 0; r < 4; ++r) rs[c][r] = 0.f;

    auto stage_s = [&](int t, int pb) {
      const int jt0 = col0 + t * 64;
      #pragma unroll
      for (int i = 0; i < 2; ++i) {
        const int s   = i * 256 + tid;
        const int col = s >> 3;
        const int cf  = (s & 7) ^ (col & 7);
        const u8* g = reps8 + (size_t)(jt0 + col) * DP + cf * 16;
        __builtin_amdgcn_global_load_lds(
            (const AS1 void*)g,
            (AS3 void*)(Bs8 + (size_t)pb * 8192 + (size_t)(i * 256 + wave * 64) * 16),
            16, 0, 0);
      }
    };

    stage_s(0, 0);
    for (int t = 0; t < 2; ++t) {
      __syncthreads();
      if (t == 0) stage_s(1, 1);
      const u8* buf = Bs8 + (size_t)(t & 1) * 8192;

      #pragma unroll
      for (int g = 0; g < 2; ++g) {
        f32x4 pacc[2][4];
        __builtin_amdgcn_s_setprio(1);
        #pragma unroll
        for (int h = 0; h < 2; ++h) {
          const int st = g * 2 + h;
          const int coln = st * 16 + l15;
          const u8* cbase = buf + (size_t)coln * DP;
          const int c0 = ((2 * quad)     ^ (coln & 7)) * 16;
          const int c1 = ((2 * quad + 1) ^ (coln & 7)) * 16;
          uint4 b0 = *(const uint4*)(cbase + c0);
          uint4 b1 = *(const uint4*)(cbase + c1);
          i32x8 bf = (i32x8){(int)b0.x, (int)b0.y, (int)b0.z, (int)b0.w,
                             (int)b1.x, (int)b1.y, (int)b1.z, (int)b1.w};
          #pragma unroll
          for (int c = 0; c < 4; ++c) {
            pacc[h][c] = __builtin_amdgcn_mfma_scale_f32_16x16x128_f8f6f4(
                af[c], bf, (f32x4){0.f, 0.f, 0.f, 0.f}, 0, 0, 0,
                0x7F7F7F7F, 0, 0x7F7F7F7F);
          }
        }
        __builtin_amdgcn_s_setprio(0);

        #pragma unroll
        for (int h = 0; h < 2; ++h) {
          float csp[4] = {0.f, 0.f, 0.f, 0.f};
          #pragma unroll
          for (int c = 0; c < 4; ++c) {
            #pragma unroll
            for (int r = 0; r < 4; ++r) {
              float ev = __builtin_amdgcn_exp2f(pacc[h][c][r] * SCALE_LOG2);
              rs[c][r] += ev;
              csp[r] += ev;
            }
          }
          if (!diag) {
            float cs = (csp[0] + csp[1]) + (csp[2] + csp[3]);
            cs += __shfl_xor(cs, 16);
            cs += __shfl_xor(cs, 32);
            if (quad == 0) csw[wave * 128 + t * 64 + (g * 2 + h) * 16 + l15] = cs;
          }
        }
      }
    }

    #pragma unroll
    for (int c = 0; c < 4; ++c) {
      const int i0 = r0 + c * 16 + quad * 4;
      #pragma unroll
      for (int r = 0; r < 4; ++r) {
        float v = rs[c][r];
        v += __shfl_xor(v, 1); v += __shfl_xor(v, 2);
        v += __shfl_xor(v, 4); v += __shfl_xor(v, 8);
        if (l15 == 0) Spart[(size_t)bxh * NTOT + i0 + r] = v;
      }
    }

    if (!diag) {
      __syncthreads();
      if (tid < 128) {
        Spart[(size_t)(2 * by) * NTOT + col0 + tid] = csw[0 * 128 + tid] + csw[1 * 128 + tid];
      } else {
        const int j = tid - 128;
        Spart[(size_t)(2 * by + 1) * NTOT + col0 + j] = csw[2 * 128 + j] + csw[3 * 128 + j];
      }
    }
  }
  grid_sync(syncc, 4);

  // ===== phase 5: rowfinal -> per-block partial sums ======================
  {
    float lsum = 0.f;
    for (int u = bid; u < 2048; u += GRID) {
      const int row = u * 4 + wave;
      const int ua = *(const unsigned short*)(reps8 + (size_t)row * DP + lane * 2);
      const int ub = *(const unsigned short*)(reps8 + (size_t)(row ^ B_ROWS) * DP + lane * 2);
      float a0 = __builtin_amdgcn_cvt_f32_fp8(ua, 0);
      float a1 = __builtin_amdgcn_cvt_f32_fp8(ua, 1);
      float b0 = __builtin_amdgcn_cvt_f32_fp8(ub, 0);
      float b1 = __builtin_amdgcn_cvt_f32_fp8(ub, 1);
      float dii = a0 * a0 + a1 * a1;
      float pos = a0 * b0 + a1 * b1;
      float ps  = Spart[(size_t)lane * NTOT + row];
      #pragma unroll
      for (int m = 1; m < 64; m <<= 1) {
        dii += __shfl_xor(dii, m);
        pos += __shfl_xor(pos, m);
        ps  += __shfl_xor(ps, m);
      }
      if (lane == 0) {
        float Si = ps - __builtin_amdgcn_exp2f(dii * SCALE_LOG2)
                      + __builtin_amdgcn_exp2f(pos * SCALE_LOG2);
        lsum += logf(Si) - pos * INV_T;
      }
    }
    __syncthreads();                       // smem reuse after sim
    float* ws = (float*)smem;
    if (lane == 0) ws[wave] = lsum;
    __syncthreads();
    if (tid == 0) partials[bid] = ws[0] + ws[1] + ws[2] + ws[3];
  }
  grid_sync(syncc, 5);

  // ===== phase 6: final mean (block 0, deterministic tree) ================
  if (bid == 0) {
    float v = partials[tid] + partials[tid + 256];
    #pragma unroll
    for (int m = 1; m < 64; m <<= 1) v += __shfl_xor(v, m);
    float* ws = (float*)smem;
    if (lane == 0) ws[wave] = v;
    __syncthreads();
    if (tid == 0) out[0] = (ws[0] + ws[1] + ws[2] + ws[3]) * (1.0f / NTOT);
  }
}

// ---------------------------------------------------------------------------
extern "C" void kernel_launch(void* const* d_in, const int* in_sizes, int n_in,
                              void* d_out, int out_size, void* d_ws, size_t ws_size,
                              hipStream_t stream) {
  const float* x_img  = (const float*)d_in[0];
  const float* x_txt  = (const float*)d_in[1];
  const float* We_img = (const float*)d_in[2];
  const float* be_img = (const float*)d_in[3];
  const float* We_txt = (const float*)d_in[4];
  const float* be_txt = (const float*)d_in[5];
  const float* W1_img = (const float*)d_in[6];
  const float* b1_img = (const float*)d_in[7];
  const float* W2_img = (const float*)d_in[8];
  const float* b2_img = (const float*)d_in[9];
  const float* W1_txt = (const float*)d_in[10];
  const float* b1_txt = (const float*)d_in[11];
  const float* W2_txt = (const float*)d_in[12];
  const float* b2_txt = (const float*)d_in[13];

  char* p = (char*)d_ws;
  bf16_t* xbf_img = (bf16_t*)p; p += (size_t)B_ROWS * DIN * 2;
  bf16_t* xbf_txt = (bf16_t*)p; p += (size_t)B_ROWS * DIN * 2;
  bf16_t* Wet_img = (bf16_t*)p; p += (size_t)DENC * DIN * 2;
  bf16_t* Wet_txt = (bf16_t*)p; p += (size_t)DENC * DIN * 2;
  bf16_t* W1t_img = (bf16_t*)p; p += (size_t)DH * DENC * 2;
  bf16_t* W1t_txt = (bf16_t*)p; p += (size_t)DH * DENC * 2;
  bf16_t* W2t_img = (bf16_t*)p; p += (size_t)DP * DH * 2;
  bf16_t* W2t_txt = (bf16_t*)p; p += (size_t)DP * DH * 2;
  bf16_t* h_img   = (bf16_t*)p; p += (size_t)B_ROWS * DENC * 2;
  bf16_t* h_txt   = (bf16_t*)p; p += (size_t)B_ROWS * DENC * 2;
  bf16_t* g_img   = (bf16_t*)p; p += (size_t)B_ROWS * DH * 2;
  bf16_t* g_txt   = (bf16_t*)p; p += (size_t)B_ROWS * DH * 2;
  u8*     reps8   = (u8*)    p; p += (size_t)NTOT * DP;
  float*  Spart   = (float*) p; p += (size_t)NSLICE * NTOT * 4;
  float*  partials= (float*) p; p += (size_t)GRID * 4;
  unsigned* syncc = (unsigned*)p; p += 1024;

  hipMemsetAsync((void*)syncc, 0, 1024, stream);
  fused_all<<<GRID, 256, 0, stream>>>(
      x_img, x_txt, We_img, We_txt, W1_img, W1_txt, W2_img, W2_txt,
      be_img, be_txt, b1_img, b1_txt, b2_img, b2_txt,
      xbf_img, xbf_txt, Wet_img, Wet_txt, W1t_img, W1t_txt, W2t_img, W2t_txt,
      h_img, h_txt, g_img, g_txt, reps8, Spart, partials, syncc,
      (float*)d_out);
}

// Round 6
// 235.604 us; speedup vs baseline: 1.6634x; 1.6634x over previous
//
#include <hip/hip_runtime.h>
#include <hip/hip_bf16.h>
#include <math.h>

typedef __bf16 bf16_t;
typedef __bf16 bf8 __attribute__((ext_vector_type(8)));
typedef __bf16 bf4 __attribute__((ext_vector_type(4)));
typedef float f32x4 __attribute__((ext_vector_type(4)));
typedef int i32x8 __attribute__((ext_vector_type(8)));
typedef unsigned char u8;

#define AS1 __attribute__((address_space(1)))
#define AS3 __attribute__((address_space(3)))

#define B_ROWS 4096
#define NTOT   8192
#define DIN    1024
#define DENC   512
#define DH     256
#define DP     128
#define NSLICE 64
#define INV_T        14.285714285714286f   // 1/0.07
#define SCALE_LOG2   20.609929155556620f   // log2(e)/0.07

__device__ __forceinline__ f32x4 mfma_16x16x32(bf8 a, bf8 b, f32x4 c) {
  return __builtin_amdgcn_mfma_f32_16x16x32_bf16(a, b, c, 0, 0, 0);
}

// ---------------------------------------------------------------------------
// R17 structure note: R5's persistent-kernel fusion REGRESSED (313us vs 140):
// software grid barriers w/ agent fences cost 30-40us each (wbl2+inv+spin)
// and L2 goes cold each phase. Kernel-boundary sync is cheaper. This round:
// 5 dispatches, fusing only block-local producer-consumer chains
// (h1+h2+norm; rowfinal+reduce via last-block-done).
// ---------------------------------------------------------------------------

// ---------------------------------------------------------------------------
// prep: blocks 0..335 weight transpose [K][N] f32 -> [N][K] bf16 (LDS tiled);
// blocks 336+ x f32->bf16 cast (2048 blocks, 4 float4/thread).
// ---------------------------------------------------------------------------
__global__ __launch_bounds__(256) void prep_kernel(
    const float* __restrict__ x_i, const float* __restrict__ x_t,
    const float* __restrict__ We_i, const float* __restrict__ We_t,
    const float* __restrict__ W1_i, const float* __restrict__ W1_t,
    const float* __restrict__ W2_i, const float* __restrict__ W2_t,
    bf16_t* __restrict__ xb_i, bf16_t* __restrict__ xb_t,
    bf16_t* __restrict__ Wet_i, bf16_t* __restrict__ Wet_t,
    bf16_t* __restrict__ W1t_i, bf16_t* __restrict__ W1t_t,
    bf16_t* __restrict__ W2t_i, bf16_t* __restrict__ W2t_t) {
  const int b = blockIdx.x;
  const int tid = threadIdx.x;
  if (b >= 336) {                          // ---- cast path
    const int base = (b - 336) * 256 + tid;
    const int HALF = (B_ROWS * DIN) / 4;   // float4 slots per modality
    #pragma unroll
    for (int it = 0; it < 4; ++it) {
      int idx = base + it * (2048 * 256);
      const float* s; bf16_t* d; int off;
      if (idx < HALF) { s = x_i; d = xb_i; off = idx; }
      else            { s = x_t; d = xb_t; off = idx - HALF; }
      float4 v = ((const float4*)s)[off];
      bf4 w = { (bf16_t)v.x, (bf16_t)v.y, (bf16_t)v.z, (bf16_t)v.w };
      ((bf4*)d)[off] = w;
    }
    return;
  }
  // ---- transpose path
  const float* src; bf16_t* dst; int K, N, tile;
  if (b < 128)      { src = We_i; dst = Wet_i; K = 1024; N = 512; tile = b; }
  else if (b < 256) { src = We_t; dst = Wet_t; K = 1024; N = 512; tile = b - 128; }
  else if (b < 288) { src = W1_i; dst = W1t_i; K = 512;  N = 256; tile = b - 256; }
  else if (b < 320) { src = W1_t; dst = W1t_t; K = 512;  N = 256; tile = b - 288; }
  else if (b < 328) { src = W2_i; dst = W2t_i; K = 256;  N = 128; tile = b - 320; }
  else              { src = W2_t; dst = W2t_t; K = 256;  N = 128; tile = b - 328; }
  const int tilesN = N >> 6;
  const int k0 = (tile / tilesN) * 64;
  const int n0 = (tile % tilesN) * 64;

  __shared__ float ld[64][65];
  #pragma unroll
  for (int i = 0; i < 4; ++i) {
    int cid = tid + i * 256;
    int r = cid >> 4;
    int c = (cid & 15) * 4;
    float4 v = *(const float4*)(src + (size_t)(k0 + r) * N + n0 + c);
    ld[r][c + 0] = v.x; ld[r][c + 1] = v.y; ld[r][c + 2] = v.z; ld[r][c + 3] = v.w;
  }
  __syncthreads();
  #pragma unroll
  for (int i = 0; i < 2; ++i) {
    int cid = tid + i * 256;
    int rn = cid >> 3;
    int c8 = (cid & 7) * 8;
    bf8 w;
    #pragma unroll
    for (int j = 0; j < 8; ++j) w[j] = (bf16_t)ld[c8 + j][rn];
    *(bf8*)(dst + (size_t)(n0 + rn) * K + k0 + c8) = w;
  }
}

// ---------------------------------------------------------------------------
// gemm_glds: bf16 GEMM, async global->LDS staging, counted-vmcnt 3-buffer
// pipeline (R15). Used only for the encoder now.
// ---------------------------------------------------------------------------
template<int MT, bool RELU>
__global__ __launch_bounds__(256) void gemm_glds(
    const bf16_t* __restrict__ A0, const bf16_t* __restrict__ A1,
    const bf16_t* __restrict__ B0, const bf16_t* __restrict__ B1,
    const float* __restrict__ bias0, const float* __restrict__ bias1,
    bf16_t* __restrict__ out0, bf16_t* __restrict__ out1,
    int N, int K) {
  const bf16_t* A   = blockIdx.z ? A1 : A0;
  const bf16_t* Bt  = blockIdx.z ? B1 : B0;
  const float* bias = blockIdx.z ? bias1 : bias0;
  bf16_t* outp      = blockIdx.z ? out1 : out0;

  const int nb   = blockIdx.x * 64;
  const int mb   = blockIdx.y * MT;
  const int tid  = threadIdx.x;
  const int wave = tid >> 6;
  const int lane = tid & 63;
  const int l15  = lane & 15;
  const int quad = lane >> 4;
  constexpr int CH = MT / 64;

  __shared__ __align__(16) bf16_t As[3][MT * 32];
  __shared__ __align__(16) bf16_t Bs[3][64 * 32];

  f32x4 acc[CH][4];
  #pragma unroll
  for (int i = 0; i < CH; ++i)
    #pragma unroll
    for (int j = 0; j < 4; ++j) acc[i][j] = (f32x4){0.f, 0.f, 0.f, 0.f};

  auto stage = [&](int k0, int pb) {
    #pragma unroll
    for (int i = 0; i < CH; ++i) {
      const int s = tid + i * 256;
      const bf16_t* ga = A + (size_t)(mb + (s >> 2)) * K + k0 + (s & 3) * 8;
      __builtin_amdgcn_global_load_lds(
          (const AS1 void*)ga,
          (AS3 void*)(As[pb] + (size_t)(wave * 64 + i * 256) * 8), 16, 0, 0);
    }
    const bf16_t* gb = Bt + (size_t)(nb + (tid >> 2)) * K + k0 + (tid & 3) * 8;
    __builtin_amdgcn_global_load_lds(
        (const AS1 void*)gb,
        (AS3 void*)(Bs[pb] + (size_t)(wave * 64) * 8), 16, 0, 0);
  };

  const int T = K >> 5;
  stage(0, 0);
  stage(32, 1);
  for (int t = 0; t < T; ++t) {
    if (t == T - 1) {
      asm volatile("s_waitcnt vmcnt(0)" ::: "memory");
    } else {
      if constexpr (CH == 2) asm volatile("s_waitcnt vmcnt(3)" ::: "memory");
      else                   asm volatile("s_waitcnt vmcnt(2)" ::: "memory");
    }
    __builtin_amdgcn_s_barrier();
    if (t + 2 < T) stage((t + 2) << 5, (t + 2) % 3);
    const bf16_t* as = As[t % 3];
    const bf16_t* bs = Bs[t % 3];
    bf8 a[CH];
    #pragma unroll
    for (int i = 0; i < CH; ++i)
      a[i] = *(const bf8*)(as + (size_t)(wave * (16 * CH) + i * 16 + l15) * 32 + quad * 8);
    #pragma unroll
    for (int nt = 0; nt < 4; ++nt) {
      bf8 bb = *(const bf8*)(bs + (size_t)(nt * 16 + l15) * 32 + quad * 8);
      #pragma unroll
      for (int i = 0; i < CH; ++i)
        acc[i][nt] = mfma_16x16x32(a[i], bb, acc[i][nt]);
    }
  }

  #pragma unroll
  for (int i = 0; i < CH; ++i) {
    const int orow = mb + wave * (16 * CH) + i * 16 + quad * 4;
    #pragma unroll
    for (int nt = 0; nt < 4; ++nt) {
      const int ocol = nb + nt * 16 + l15;
      const float bval = bias[ocol];
      #pragma unroll
      for (int r = 0; r < 4; ++r) {
        float v = acc[i][nt][r] + bval;
        if (RELU) v = fmaxf(v, 0.f);
        outp[(size_t)(orow + r) * N + ocol] = (bf16_t)v;
      }
    }
  }
}

// ---------------------------------------------------------------------------
// head12_norm (R17): fused g = relu(h@W1+b1); z = g@W2+b2; L2-norm -> fp8.
// One 16-row block does the whole chain; g lives in LDS (no global round
// trip, one dispatch instead of two). K-chunk accumulation order identical
// to the R4 pair -> bit-identical reps8.
//   LDS: h 16K | W1 ktile dbuf 32K | g [16][264] 8.25K | W2 ktile dbuf 16K.
//   73 KB -> 2 blocks/CU; 512 blocks all resident.
// ---------------------------------------------------------------------------
__global__ __launch_bounds__(256) void head12_norm(
    const bf16_t* __restrict__ h_i, const bf16_t* __restrict__ h_t,
    const bf16_t* __restrict__ W1t_i, const bf16_t* __restrict__ W1t_t,
    const bf16_t* __restrict__ W2t_i, const bf16_t* __restrict__ W2t_t,
    const float* __restrict__ b1_i, const float* __restrict__ b1_t,
    const float* __restrict__ b2_i, const float* __restrict__ b2_t,
    u8* __restrict__ reps8) {
  const int z  = blockIdx.z;
  const int mb = blockIdx.x * 16;
  const bf16_t* H   = z ? h_t : h_i;
  const bf16_t* W1t = z ? W1t_t : W1t_i;
  const bf16_t* W2t = z ? W2t_t : W2t_i;
  const float*  b1  = z ? b1_t : b1_i;
  const float*  b2  = z ? b2_t : b2_i;

  const int tid  = threadIdx.x;
  const int wave = tid >> 6;
  const int lane = tid & 63;
  const int l15  = lane & 15;
  const int quad = lane >> 4;

  __shared__ __align__(16) bf16_t As[16 * 512];      // 16 KB (h tile, 16 kt)
  __shared__ __align__(16) bf16_t B1s[2][256 * 32];  // 32 KB (W1 ktile dbuf)
  __shared__ __align__(16) bf16_t G[16 * 264];       // 8.25 KB (g, padded)
  __shared__ __align__(16) bf16_t B2s[2][128 * 32];  // 16 KB (W2 ktile dbuf)
  __shared__ float ssL[64];

  // ---- stage h whole-K: 1024 slots of 16B (4/thread), XOR chunk swizzle
  #pragma unroll
  for (int i = 0; i < 4; ++i) {
    const int s = i * 256 + tid;
    const int kt = s >> 6, rem = s & 63, row = rem >> 2, j = rem & 3;
    const int cf = j ^ (row & 3);
    const bf16_t* ga = H + (size_t)(mb + row) * DENC + kt * 32 + cf * 8;
    __builtin_amdgcn_global_load_lds(
        (const AS1 void*)ga, (AS3 void*)(As + (size_t)(i * 256 + wave * 64) * 8),
        16, 0, 0);
  }
  auto stage_w1 = [&](int kt, int pb) {    // 1024 slots of 16B (4/thread)
    #pragma unroll
    for (int i = 0; i < 4; ++i) {
      const int s = i * 256 + tid;
      const int col = s >> 2, j = s & 3, cf = j ^ (col & 3);
      const bf16_t* gb = W1t + (size_t)col * DENC + kt * 32 + cf * 8;
      __builtin_amdgcn_global_load_lds(
          (const AS1 void*)gb,
          (AS3 void*)(B1s[pb] + (size_t)(i * 256 + wave * 64) * 8), 16, 0, 0);
    }
  };

  stage_w1(0, 0);
  f32x4 acc1[4];
  #pragma unroll
  for (int nt = 0; nt < 4; ++nt) acc1[nt] = (f32x4){0.f, 0.f, 0.f, 0.f};
  const int wc0 = wave * 64;               // GEMM1: wave covers 64 of 256 cols
  for (int kt = 0; kt < 16; ++kt) {
    __syncthreads();                       // tile kt (and h) resident
    if (kt < 15) stage_w1(kt + 1, (kt + 1) & 1);
    const bf16_t* bs = B1s[kt & 1];
    bf8 a = *(const bf8*)(As + (size_t)kt * 512 +
                          (size_t)(l15 * 4 + (quad ^ (l15 & 3))) * 8);
    #pragma unroll
    for (int nt = 0; nt < 4; ++nt) {
      const int col = wc0 + nt * 16 + l15;
      bf8 bb = *(const bf8*)(bs + (size_t)(col * 4 + (quad ^ (col & 3))) * 8);
      acc1[nt] = mfma_16x16x32(a, bb, acc1[nt]);
    }
  }

  auto stage_w2 = [&](int kt2, int pb) {   // 512 slots of 16B (2/thread)
    #pragma unroll
    for (int i = 0; i < 2; ++i) {
      const int s = i * 256 + tid;
      const int col = s >> 2, j = s & 3, cf = j ^ (col & 3);
      const bf16_t* gb = W2t + (size_t)col * DH + kt2 * 32 + cf * 8;
      __builtin_amdgcn_global_load_lds(
          (const AS1 void*)gb,
          (AS3 void*)(B2s[pb] + (size_t)(i * 256 + wave * 64) * 8), 16, 0, 0);
    }
  };
  stage_w2(0, 0);                          // overlap with g write

  // ---- bias + relu -> g in LDS (bf16, row-major [16][264], 16B-aligned rows)
  #pragma unroll
  for (int nt = 0; nt < 4; ++nt) {
    const int col = wc0 + nt * 16 + l15;
    const float bv = b1[col];
    #pragma unroll
    for (int r = 0; r < 4; ++r) {
      float v = fmaxf(acc1[nt][r] + bv, 0.f);
      G[(size_t)(quad * 4 + r) * 264 + col] = (bf16_t)v;
    }
  }

  f32x4 acc2[2];
  acc2[0] = (f32x4){0.f, 0.f, 0.f, 0.f};
  acc2[1] = (f32x4){0.f, 0.f, 0.f, 0.f};
  const int wc2 = wave * 32;               // GEMM2: wave covers 32 of 128 cols
  for (int kt2 = 0; kt2 < 8; ++kt2) {
    __syncthreads();                       // W2 tile + (first iter) g visible
    if (kt2 < 7) stage_w2(kt2 + 1, (kt2 + 1) & 1);
    const bf16_t* bs = B2s[kt2 & 1];
    bf8 a = *(const bf8*)(G + (size_t)l15 * 264 + kt2 * 32 + quad * 8);
    #pragma unroll
    for (int nt = 0; nt < 2; ++nt) {
      const int col = wc2 + nt * 16 + l15;
      bf8 bb = *(const bf8*)(bs + (size_t)(col * 4 + (quad ^ (col & 3))) * 8);
      acc2[nt] = mfma_16x16x32(a, bb, acc2[nt]);
    }
  }

  // ---- L2 norm + fp8 pack (verbatim R4 tail)
  float ssp[4];
  #pragma unroll
  for (int r = 0; r < 4; ++r) {
    #pragma unroll
    for (int nt = 0; nt < 2; ++nt) acc2[nt][r] += b2[wc2 + nt * 16 + l15];
    float s = acc2[0][r] * acc2[0][r] + acc2[1][r] * acc2[1][r];
    s += __shfl_xor(s, 1); s += __shfl_xor(s, 2);
    s += __shfl_xor(s, 4); s += __shfl_xor(s, 8);
    ssp[r] = s;
  }
  if (l15 == 0) {
    #pragma unroll
    for (int r = 0; r < 4; ++r) ssL[wave * 16 + quad * 4 + r] = ssp[r];
  }
  __syncthreads();
  const size_t gr0 = (size_t)(z ? B_ROWS : 0) + mb + quad * 4;
  #pragma unroll
  for (int r = 0; r < 4; ++r) {
    const int row = quad * 4 + r;
    float tot = ssL[row] + ssL[16 + row] + ssL[32 + row] + ssL[48 + row];
    const float inv = 1.0f / fmaxf(sqrtf(tot), 1e-12f);
    int pk = __builtin_amdgcn_cvt_pk_fp8_f32(acc2[0][r] * inv, acc2[1][r] * inv, 0, 0);
    reps8[(gr0 + r) * DP + wc2 + l15]      = (u8)(pk & 0xff);
    reps8[(gr0 + r) * DP + wc2 + 16 + l15] = (u8)((pk >> 8) & 0xff);
  }
}

// ---------------------------------------------------------------------------
// sim_fp8 (R4-verified): upper-triangle symmetry, two-phase MFMA/exp,
// 256x128 blocks (1056, ~4.1/CU), 64 VGPR.
// ---------------------------------------------------------------------------
__global__ __launch_bounds__(256, 4) void sim_fp8_kernel(
    const u8* __restrict__ reps8, float* __restrict__ Spart) {
  const int l = blockIdx.x;
  int by = (int)((65.0f - sqrtf(4225.0f - 4.0f * (float)l)) * 0.5f);
  while ((by + 1) * (65 - (by + 1)) <= l) ++by;
  while (by * (65 - by) > l) --by;
  const int bxh = 2 * by + (l - by * (65 - by));
  const bool diag = (bxh - 2 * by) < 2;
  const int rowbase = by * 256;
  const int col0    = bxh * 128;
  const int tid  = threadIdx.x;
  const int wave = tid >> 6;
  const int lane = tid & 63;
  const int l15  = lane & 15;
  const int quad = lane >> 4;

  __shared__ __align__(16) u8 Bs[2][64 * DP];
  __shared__ float csw[4][128];

  const int r0 = rowbase + wave * 64;
  i32x8 af[4];
  #pragma unroll
  for (int c = 0; c < 4; ++c) {
    const uint4* ap = (const uint4*)(reps8 + (size_t)(r0 + c * 16 + l15) * DP + quad * 32);
    uint4 x0 = ap[0], x1 = ap[1];
    af[c] = (i32x8){(int)x0.x, (int)x0.y, (int)x0.z, (int)x0.w,
                    (int)x1.x, (int)x1.y, (int)x1.z, (int)x1.w};
  }

  float rs[4][4];
  #pragma unroll
  for (int c = 0; c < 4; ++c)
    #pragma unroll
    for (int r = 0; r < 4; ++r) rs[c][r] = 0.f;

  auto stage = [&](int t, int pb) {
    const int jt0 = col0 + t * 64;
    #pragma unroll
    for (int i = 0; i < 2; ++i) {
      const int s   = i * 256 + tid;
      const int col = s >> 3;
      const int cf  = (s & 7) ^ (col & 7);
      const u8* g = reps8 + (size_t)(jt0 + col) * DP + cf * 16;
      __builtin_amdgcn_global_load_lds(
          (const AS1 void*)g,
          (AS3 void*)(Bs[pb] + (size_t)(i * 256 + wave * 64) * 16), 16, 0, 0);
    }
  };

  stage(0, 0);
  for (int t = 0; t < 2; ++t) {
    __syncthreads();
    if (t == 0) stage(1, 1);
    const u8* buf = Bs[t & 1];

    #pragma unroll
    for (int g = 0; g < 2; ++g) {
      f32x4 pacc[2][4];
      __builtin_amdgcn_s_setprio(1);
      #pragma unroll
      for (int h = 0; h < 2; ++h) {
        const int st = g * 2 + h;
        const int coln = st * 16 + l15;
        const u8* cbase = buf + (size_t)coln * DP;
        const int c0 = ((2 * quad)     ^ (coln & 7)) * 16;
        const int c1 = ((2 * quad + 1) ^ (coln & 7)) * 16;
        uint4 b0 = *(const uint4*)(cbase + c0);
        uint4 b1 = *(const uint4*)(cbase + c1);
        i32x8 bf = (i32x8){(int)b0.x, (int)b0.y, (int)b0.z, (int)b0.w,
                           (int)b1.x, (int)b1.y, (int)b1.z, (int)b1.w};
        #pragma unroll
        for (int c = 0; c < 4; ++c) {
          pacc[h][c] = __builtin_amdgcn_mfma_scale_f32_16x16x128_f8f6f4(
              af[c], bf, (f32x4){0.f, 0.f, 0.f, 0.f}, 0, 0, 0,
              0x7F7F7F7F, 0, 0x7F7F7F7F);
        }
      }
      __builtin_amdgcn_s_setprio(0);

      #pragma unroll
      for (int h = 0; h < 2; ++h) {
        float csp[4] = {0.f, 0.f, 0.f, 0.f};
        #pragma unroll
        for (int c = 0; c < 4; ++c) {
          #pragma unroll
          for (int r = 0; r < 4; ++r) {
            float ev = __builtin_amdgcn_exp2f(pacc[h][c][r] * SCALE_LOG2);
            rs[c][r] += ev;
            csp[r] += ev;
          }
        }
        if (!diag) {
          float cs = (csp[0] + csp[1]) + (csp[2] + csp[3]);
          cs += __shfl_xor(cs, 16);
          cs += __shfl_xor(cs, 32);
          if (quad == 0) csw[wave][t * 64 + (g * 2 + h) * 16 + l15] = cs;
        }
      }
    }
  }

  #pragma unroll
  for (int c = 0; c < 4; ++c) {
    const int i0 = r0 + c * 16 + quad * 4;
    #pragma unroll
    for (int r = 0; r < 4; ++r) {
      float v = rs[c][r];
      v += __shfl_xor(v, 1); v += __shfl_xor(v, 2);
      v += __shfl_xor(v, 4); v += __shfl_xor(v, 8);
      if (l15 == 0) Spart[(size_t)bxh * NTOT + i0 + r] = v;
    }
  }

  if (!diag) {
    __syncthreads();
    if (tid < 128) {
      Spart[(size_t)(2 * by) * NTOT + col0 + tid] = csw[0][tid] + csw[1][tid];
    } else {
      const int j = tid - 128;
      Spart[(size_t)(2 * by + 1) * NTOT + col0 + j] = csw[2][j] + csw[3][j];
    }
  }
}

// ---------------------------------------------------------------------------
// rowfinal_reduce (R17): per-row loss + mean in ONE dispatch via the
// last-block-done pattern. Block partial -> device-scope atomic store;
// ACQ_REL counter RMW; last block sums partials in FIXED index order
// (deterministic) and writes the mean. No grid barrier, no L2 flush.
// ---------------------------------------------------------------------------
__global__ __launch_bounds__(256) void rowfinal_reduce(
    const u8* __restrict__ reps8, const float* __restrict__ Spart,
    float* __restrict__ partials, unsigned* __restrict__ syncc,
    float* __restrict__ out) {
  const int tid  = threadIdx.x;
  const int wave = tid >> 6;
  const int lane = tid & 63;
  const int row  = blockIdx.x * 4 + wave;
  const int ua = *(const unsigned short*)(reps8 + (size_t)row * DP + lane * 2);
  const int ub = *(const unsigned short*)(reps8 + (size_t)(row ^ B_ROWS) * DP + lane * 2);
  float a0 = __builtin_amdgcn_cvt_f32_fp8(ua, 0);
  float a1 = __builtin_amdgcn_cvt_f32_fp8(ua, 1);
  float b0 = __builtin_amdgcn_cvt_f32_fp8(ub, 0);
  float b1 = __builtin_amdgcn_cvt_f32_fp8(ub, 1);
  float dii = a0 * a0 + a1 * a1;
  float pos = a0 * b0 + a1 * b1;
  float ps  = Spart[(size_t)lane * NTOT + row];
  #pragma unroll
  for (int m = 1; m < 64; m <<= 1) {
    dii += __shfl_xor(dii, m);
    pos += __shfl_xor(pos, m);
    ps  += __shfl_xor(ps, m);
  }
  __shared__ float ws[4];
  __shared__ int isLast;
  if (lane == 0) {
    float Si = ps - __builtin_amdgcn_exp2f(dii * SCALE_LOG2)
                  + __builtin_amdgcn_exp2f(pos * SCALE_LOG2);
    ws[wave] = logf(Si) - pos * INV_T;
  }
  __syncthreads();
  if (tid == 0) {
    float p = (ws[0] + ws[1]) + (ws[2] + ws[3]);
    __hip_atomic_store(&partials[blockIdx.x], p, __ATOMIC_RELAXED,
                       __HIP_MEMORY_SCOPE_AGENT);
    unsigned prev = __hip_atomic_fetch_add(&syncc[0], 1u, __ATOMIC_ACQ_REL,
                                           __HIP_MEMORY_SCOPE_AGENT);
    isLast = (prev == (unsigned)(NTOT / 4 - 1));
  }
  __syncthreads();
  if (isLast) {
    float s = 0.f;
    for (int i = tid; i < NTOT / 4; i += 256)   // fixed order per thread
      s += __hip_atomic_load(&partials[i], __ATOMIC_RELAXED,
                             __HIP_MEMORY_SCOPE_AGENT);
    #pragma unroll
    for (int m = 1; m < 64; m <<= 1) s += __shfl_xor(s, m);
    __shared__ float w2[4];
    if (lane == 0) w2[wave] = s;
    __syncthreads();
    if (tid == 0) out[0] = ((w2[0] + w2[1]) + (w2[2] + w2[3])) * (1.0f / NTOT);
  }
}

// ---------------------------------------------------------------------------
extern "C" void kernel_launch(void* const* d_in, const int* in_sizes, int n_in,
                              void* d_out, int out_size, void* d_ws, size_t ws_size,
                              hipStream_t stream) {
  const float* x_img  = (const float*)d_in[0];
  const float* x_txt  = (const float*)d_in[1];
  const float* We_img = (const float*)d_in[2];
  const float* be_img = (const float*)d_in[3];
  const float* We_txt = (const float*)d_in[4];
  const float* be_txt = (const float*)d_in[5];
  const float* W1_img = (const float*)d_in[6];
  const float* b1_img = (const float*)d_in[7];
  const float* W2_img = (const float*)d_in[8];
  const float* b2_img = (const float*)d_in[9];
  const float* W1_txt = (const float*)d_in[10];
  const float* b1_txt = (const float*)d_in[11];
  const float* W2_txt = (const float*)d_in[12];
  const float* b2_txt = (const float*)d_in[13];

  char* p = (char*)d_ws;
  bf16_t* xbf_img = (bf16_t*)p; p += (size_t)B_ROWS * DIN * 2;
  bf16_t* xbf_txt = (bf16_t*)p; p += (size_t)B_ROWS * DIN * 2;
  bf16_t* Wet_img = (bf16_t*)p; p += (size_t)DENC * DIN * 2;
  bf16_t* Wet_txt = (bf16_t*)p; p += (size_t)DENC * DIN * 2;
  bf16_t* W1t_img = (bf16_t*)p; p += (size_t)DH * DENC * 2;
  bf16_t* W1t_txt = (bf16_t*)p; p += (size_t)DH * DENC * 2;
  bf16_t* W2t_img = (bf16_t*)p; p += (size_t)DP * DH * 2;
  bf16_t* W2t_txt = (bf16_t*)p; p += (size_t)DP * DH * 2;
  bf16_t* h_img   = (bf16_t*)p; p += (size_t)B_ROWS * DENC * 2;
  bf16_t* h_txt   = (bf16_t*)p; p += (size_t)B_ROWS * DENC * 2;
  u8*     reps8   = (u8*)    p; p += (size_t)NTOT * DP;
  float*  Spart   = (float*) p; p += (size_t)NSLICE * NTOT * 4;
  float*  partials= (float*) p; p += (size_t)(NTOT / 4) * 4;
  unsigned* syncc = (unsigned*)p; p += 64;

  hipMemsetAsync((void*)syncc, 0, 64, stream);

  prep_kernel<<<336 + 2048, 256, 0, stream>>>(
      x_img, x_txt, We_img, We_txt, W1_img, W1_txt, W2_img, W2_txt,
      xbf_img, xbf_txt, Wet_img, Wet_txt, W1t_img, W1t_txt, W2t_img, W2t_txt);

  // encoder: h = x @ We + be   [4096x512], K=1024 (counted-vmcnt pipeline)
  gemm_glds<128, false><<<dim3(DENC / 64, B_ROWS / 128, 2), 256, 0, stream>>>(
      xbf_img, xbf_txt, Wet_img, Wet_txt, be_img, be_txt, h_img, h_txt,
      DENC, DIN);
  // head1 + head2 + norm fused -> fp8 reps8 (g stays in LDS)
  head12_norm<<<dim3(B_ROWS / 16, 1, 2), 256, 0, stream>>>(
      h_img, h_txt, W1t_img, W1t_txt, W2t_img, W2t_txt,
      b1_img, b1_txt, b2_img, b2_txt, reps8);

  // sim partials via MX-fp8 K=128 MFMA — 256x128 upper-triangle blocks
  sim_fp8_kernel<<<dim3(1056), 256, 0, stream>>>(reps8, Spart);
  // per-row loss + mean, one dispatch (last-block-done)
  rowfinal_reduce<<<NTOT / 4, 256, 0, stream>>>(
      reps8, Spart, partials, syncc, (float*)d_out);
}

// Round 7
// 185.173 us; speedup vs baseline: 2.1164x; 1.2723x over previous
//
#include <hip/hip_runtime.h>
#include <hip/hip_bf16.h>
#include <math.h>

typedef __bf16 bf16_t;
typedef __bf16 bf8 __attribute__((ext_vector_type(8)));
typedef __bf16 bf4 __attribute__((ext_vector_type(4)));
typedef float f32x4 __attribute__((ext_vector_type(4)));
typedef int i32x8 __attribute__((ext_vector_type(8)));
typedef unsigned char u8;

#define AS1 __attribute__((address_space(1)))
#define AS3 __attribute__((address_space(3)))

#define B_ROWS 4096
#define NTOT   8192
#define DIN    1024
#define DENC   512
#define DH     256
#define DP     128
#define NSLICE 64
#define INV_T        14.285714285714286f   // 1/0.07
#define SCALE_LOG2   20.609929155556620f   // log2(e)/0.07

__device__ __forceinline__ f32x4 mfma_16x16x32(bf8 a, bf8 b, f32x4 c) {
  return __builtin_amdgcn_mfma_f32_16x16x32_bf16(a, b, c, 0, 0, 0);
}

// ---------------------------------------------------------------------------
// R18 structure notes:
//  - R5/R6 lesson: agent-scope fences/atomics trigger L2 maintenance on
//    gfx950 — 30-60us per use site. NO device-scope sync anywhere; kernel
//    boundaries are the only cross-block sync.
//  - R6 lesson: rowfinal's Spart[slice][row] gather = 64 cache lines/wave
//    (8.7 MB FETCH, latency-bound, ~35-58us — hidden below the fill cutoff
//    since R3). Fix: Spart stored [row][slice] -> one coalesced 256 B load
//    per wave. sim's 4 B scattered stores are absorbed by L2 byte-masking.
//  - head12 fusion reverted (24 vmcnt(0) drains at 2 blk/CU regressed).
// ---------------------------------------------------------------------------

// ---------------------------------------------------------------------------
// prep: blocks 0..335 weight transpose [K][N] f32 -> [N][K] bf16 (LDS tiled);
// blocks 336+ x f32->bf16 cast (2048 blocks, 4 float4/thread).
// ---------------------------------------------------------------------------
__global__ __launch_bounds__(256) void prep_kernel(
    const float* __restrict__ x_i, const float* __restrict__ x_t,
    const float* __restrict__ We_i, const float* __restrict__ We_t,
    const float* __restrict__ W1_i, const float* __restrict__ W1_t,
    const float* __restrict__ W2_i, const float* __restrict__ W2_t,
    bf16_t* __restrict__ xb_i, bf16_t* __restrict__ xb_t,
    bf16_t* __restrict__ Wet_i, bf16_t* __restrict__ Wet_t,
    bf16_t* __restrict__ W1t_i, bf16_t* __restrict__ W1t_t,
    bf16_t* __restrict__ W2t_i, bf16_t* __restrict__ W2t_t) {
  const int b = blockIdx.x;
  const int tid = threadIdx.x;
  if (b >= 336) {                          // ---- cast path
    const int base = (b - 336) * 256 + tid;
    const int HALF = (B_ROWS * DIN) / 4;   // float4 slots per modality
    #pragma unroll
    for (int it = 0; it < 4; ++it) {
      int idx = base + it * (2048 * 256);
      const float* s; bf16_t* d; int off;
      if (idx < HALF) { s = x_i; d = xb_i; off = idx; }
      else            { s = x_t; d = xb_t; off = idx - HALF; }
      float4 v = ((const float4*)s)[off];
      bf4 w = { (bf16_t)v.x, (bf16_t)v.y, (bf16_t)v.z, (bf16_t)v.w };
      ((bf4*)d)[off] = w;
    }
    return;
  }
  // ---- transpose path
  const float* src; bf16_t* dst; int K, N, tile;
  if (b < 128)      { src = We_i; dst = Wet_i; K = 1024; N = 512; tile = b; }
  else if (b < 256) { src = We_t; dst = Wet_t; K = 1024; N = 512; tile = b - 128; }
  else if (b < 288) { src = W1_i; dst = W1t_i; K = 512;  N = 256; tile = b - 256; }
  else if (b < 320) { src = W1_t; dst = W1t_t; K = 512;  N = 256; tile = b - 288; }
  else if (b < 328) { src = W2_i; dst = W2t_i; K = 256;  N = 128; tile = b - 320; }
  else              { src = W2_t; dst = W2t_t; K = 256;  N = 128; tile = b - 328; }
  const int tilesN = N >> 6;
  const int k0 = (tile / tilesN) * 64;
  const int n0 = (tile % tilesN) * 64;

  __shared__ float ld[64][65];
  #pragma unroll
  for (int i = 0; i < 4; ++i) {
    int cid = tid + i * 256;
    int r = cid >> 4;
    int c = (cid & 15) * 4;
    float4 v = *(const float4*)(src + (size_t)(k0 + r) * N + n0 + c);
    ld[r][c + 0] = v.x; ld[r][c + 1] = v.y; ld[r][c + 2] = v.z; ld[r][c + 3] = v.w;
  }
  __syncthreads();
  #pragma unroll
  for (int i = 0; i < 2; ++i) {
    int cid = tid + i * 256;
    int rn = cid >> 3;
    int c8 = (cid & 7) * 8;
    bf8 w;
    #pragma unroll
    for (int j = 0; j < 8; ++j) w[j] = (bf16_t)ld[c8 + j][rn];
    *(bf8*)(dst + (size_t)(n0 + rn) * K + k0 + c8) = w;
  }
}

// ---------------------------------------------------------------------------
// gemm_glds: bf16 GEMM, async global->LDS staging, counted-vmcnt 3-buffer
// pipeline (R15-verified). Encoder + head1.
// ---------------------------------------------------------------------------
template<int MT, bool RELU>
__global__ __launch_bounds__(256) void gemm_glds(
    const bf16_t* __restrict__ A0, const bf16_t* __restrict__ A1,
    const bf16_t* __restrict__ B0, const bf16_t* __restrict__ B1,
    const float* __restrict__ bias0, const float* __restrict__ bias1,
    bf16_t* __restrict__ out0, bf16_t* __restrict__ out1,
    int N, int K) {
  const bf16_t* A   = blockIdx.z ? A1 : A0;
  const bf16_t* Bt  = blockIdx.z ? B1 : B0;
  const float* bias = blockIdx.z ? bias1 : bias0;
  bf16_t* outp      = blockIdx.z ? out1 : out0;

  const int nb   = blockIdx.x * 64;
  const int mb   = blockIdx.y * MT;
  const int tid  = threadIdx.x;
  const int wave = tid >> 6;
  const int lane = tid & 63;
  const int l15  = lane & 15;
  const int quad = lane >> 4;
  constexpr int CH = MT / 64;

  __shared__ __align__(16) bf16_t As[3][MT * 32];
  __shared__ __align__(16) bf16_t Bs[3][64 * 32];

  f32x4 acc[CH][4];
  #pragma unroll
  for (int i = 0; i < CH; ++i)
    #pragma unroll
    for (int j = 0; j < 4; ++j) acc[i][j] = (f32x4){0.f, 0.f, 0.f, 0.f};

  auto stage = [&](int k0, int pb) {
    #pragma unroll
    for (int i = 0; i < CH; ++i) {
      const int s = tid + i * 256;
      const bf16_t* ga = A + (size_t)(mb + (s >> 2)) * K + k0 + (s & 3) * 8;
      __builtin_amdgcn_global_load_lds(
          (const AS1 void*)ga,
          (AS3 void*)(As[pb] + (size_t)(wave * 64 + i * 256) * 8), 16, 0, 0);
    }
    const bf16_t* gb = Bt + (size_t)(nb + (tid >> 2)) * K + k0 + (tid & 3) * 8;
    __builtin_amdgcn_global_load_lds(
        (const AS1 void*)gb,
        (AS3 void*)(Bs[pb] + (size_t)(wave * 64) * 8), 16, 0, 0);
  };

  const int T = K >> 5;
  stage(0, 0);
  stage(32, 1);
  for (int t = 0; t < T; ++t) {
    if (t == T - 1) {
      asm volatile("s_waitcnt vmcnt(0)" ::: "memory");
    } else {
      if constexpr (CH == 2) asm volatile("s_waitcnt vmcnt(3)" ::: "memory");
      else                   asm volatile("s_waitcnt vmcnt(2)" ::: "memory");
    }
    __builtin_amdgcn_s_barrier();
    if (t + 2 < T) stage((t + 2) << 5, (t + 2) % 3);
    const bf16_t* as = As[t % 3];
    const bf16_t* bs = Bs[t % 3];
    bf8 a[CH];
    #pragma unroll
    for (int i = 0; i < CH; ++i)
      a[i] = *(const bf8*)(as + (size_t)(wave * (16 * CH) + i * 16 + l15) * 32 + quad * 8);
    #pragma unroll
    for (int nt = 0; nt < 4; ++nt) {
      bf8 bb = *(const bf8*)(bs + (size_t)(nt * 16 + l15) * 32 + quad * 8);
      #pragma unroll
      for (int i = 0; i < CH; ++i)
        acc[i][nt] = mfma_16x16x32(a[i], bb, acc[i][nt]);
    }
  }

  #pragma unroll
  for (int i = 0; i < CH; ++i) {
    const int orow = mb + wave * (16 * CH) + i * 16 + quad * 4;
    #pragma unroll
    for (int nt = 0; nt < 4; ++nt) {
      const int ocol = nb + nt * 16 + l15;
      const float bval = bias[ocol];
      #pragma unroll
      for (int r = 0; r < 4; ++r) {
        float v = acc[i][nt][r] + bval;
        if (RELU) v = fmaxf(v, 0.f);
        outp[(size_t)(orow + r) * N + ocol] = (bf16_t)v;
      }
    }
  }
}

// ---------------------------------------------------------------------------
// head2_norm (R15-verified stage-once): z = g @ W2t^T + b2 + fused L2 norm
// -> fp8 reps8. Whole K=256 in LDS (A 8 KB + W2t 64 KB), ONE barrier.
// ---------------------------------------------------------------------------
__global__ __launch_bounds__(256) void head2_norm(
    const bf16_t* __restrict__ A0, const bf16_t* __restrict__ A1,
    const bf16_t* __restrict__ B0, const bf16_t* __restrict__ B1,
    const float* __restrict__ bias0, const float* __restrict__ bias1,
    u8* __restrict__ reps8) {
  const bf16_t* A   = blockIdx.z ? A1 : A0;
  const bf16_t* Bt  = blockIdx.z ? B1 : B0;
  const float* bias = blockIdx.z ? bias1 : bias0;

  const int mb   = blockIdx.x * 16;
  const int tid  = threadIdx.x;
  const int wave = tid >> 6;
  const int lane = tid & 63;
  const int l15  = lane & 15;
  const int quad = lane >> 4;
  const int wc0  = wave * 32;

  __shared__ __align__(16) bf16_t Asb[8 * 16 * 32];    // 8 KB
  __shared__ __align__(16) bf16_t Bsb[8 * 128 * 32];   // 64 KB
  __shared__ float ssL[64];

  #pragma unroll
  for (int i = 0; i < 2; ++i) {
    const int s = i * 256 + tid;
    const int kt = s >> 6, slot = s & 63;
    const int row = slot >> 2, j = slot & 3, cf = j ^ (row & 3);
    const bf16_t* ga = A + (size_t)(mb + row) * DH + kt * 32 + cf * 8;
    __builtin_amdgcn_global_load_lds(
        (const AS1 void*)ga,
        (AS3 void*)(Asb + (size_t)(i * 256 + wave * 64) * 8), 16, 0, 0);
  }
  #pragma unroll
  for (int i = 0; i < 16; ++i) {
    const int s2 = i * 256 + tid;
    const int kt = s2 >> 9, slot = s2 & 511;
    const int col = slot >> 2, j = slot & 3, cf = j ^ (col & 3);
    const bf16_t* gb = Bt + (size_t)col * DH + kt * 32 + cf * 8;
    __builtin_amdgcn_global_load_lds(
        (const AS1 void*)gb,
        (AS3 void*)(Bsb + (size_t)(i * 256 + wave * 64) * 8), 16, 0, 0);
  }
  __syncthreads();                         // single drain for the whole K

  f32x4 acc[2];
  acc[0] = (f32x4){0.f, 0.f, 0.f, 0.f};
  acc[1] = (f32x4){0.f, 0.f, 0.f, 0.f};
  #pragma unroll
  for (int kt = 0; kt < 8; ++kt) {
    bf8 a = *(const bf8*)(Asb + (size_t)kt * 512 +
                          (size_t)(l15 * 4 + (quad ^ (l15 & 3))) * 8);
    #pragma unroll
    for (int nt = 0; nt < 2; ++nt) {
      const int col = wc0 + nt * 16 + l15;
      bf8 bb = *(const bf8*)(Bsb + (size_t)kt * 4096 +
                             (size_t)(col * 4 + (quad ^ (col & 3))) * 8);
      acc[nt] = mfma_16x16x32(a, bb, acc[nt]);
    }
  }

  float ssp[4];
  #pragma unroll
  for (int r = 0; r < 4; ++r) {
    #pragma unroll
    for (int nt = 0; nt < 2; ++nt) acc[nt][r] += bias[wc0 + nt * 16 + l15];
    float s = acc[0][r] * acc[0][r] + acc[1][r] * acc[1][r];
    s += __shfl_xor(s, 1); s += __shfl_xor(s, 2);
    s += __shfl_xor(s, 4); s += __shfl_xor(s, 8);
    ssp[r] = s;
  }
  if (l15 == 0) {
    #pragma unroll
    for (int r = 0; r < 4; ++r) ssL[wave * 16 + quad * 4 + r] = ssp[r];
  }
  __syncthreads();
  const size_t gr0 = (size_t)(blockIdx.z ? B_ROWS : 0) + mb + quad * 4;
  #pragma unroll
  for (int r = 0; r < 4; ++r) {
    const int row = quad * 4 + r;
    float tot = ssL[row] + ssL[16 + row] + ssL[32 + row] + ssL[48 + row];
    const float inv = 1.0f / fmaxf(sqrtf(tot), 1e-12f);
    int pk = __builtin_amdgcn_cvt_pk_fp8_f32(acc[0][r] * inv, acc[1][r] * inv, 0, 0);
    reps8[(gr0 + r) * DP + wc0 + l15]      = (u8)(pk & 0xff);
    reps8[(gr0 + r) * DP + wc0 + 16 + l15] = (u8)((pk >> 8) & 0xff);
  }
}

// ---------------------------------------------------------------------------
// sim_fp8 (R4-verified core): upper-triangle symmetry, two-phase MFMA/exp,
// 256x128 blocks (1056, ~4.1/CU). R18: Spart is now [row][NSLICE] — writes
// become 4 B scatters (L2 byte-mask merged), reads in rowfinal coalesce.
// ---------------------------------------------------------------------------
__global__ __launch_bounds__(256, 4) void sim_fp8_kernel(
    const u8* __restrict__ reps8, float* __restrict__ Spart) {
  const int l = blockIdx.x;
  int by = (int)((65.0f - sqrtf(4225.0f - 4.0f * (float)l)) * 0.5f);
  while ((by + 1) * (65 - (by + 1)) <= l) ++by;
  while (by * (65 - by) > l) --by;
  const int bxh = 2 * by + (l - by * (65 - by));
  const bool diag = (bxh - 2 * by) < 2;
  const int rowbase = by * 256;
  const int col0    = bxh * 128;
  const int tid  = threadIdx.x;
  const int wave = tid >> 6;
  const int lane = tid & 63;
  const int l15  = lane & 15;
  const int quad = lane >> 4;

  __shared__ __align__(16) u8 Bs[2][64 * DP];
  __shared__ float csw[4][128];

  const int r0 = rowbase + wave * 64;
  i32x8 af[4];
  #pragma unroll
  for (int c = 0; c < 4; ++c) {
    const uint4* ap = (const uint4*)(reps8 + (size_t)(r0 + c * 16 + l15) * DP + quad * 32);
    uint4 x0 = ap[0], x1 = ap[1];
    af[c] = (i32x8){(int)x0.x, (int)x0.y, (int)x0.z, (int)x0.w,
                    (int)x1.x, (int)x1.y, (int)x1.z, (int)x1.w};
  }

  float rs[4][4];
  #pragma unroll
  for (int c = 0; c < 4; ++c)
    #pragma unroll
    for (int r = 0; r < 4; ++r) rs[c][r] = 0.f;

  auto stage = [&](int t, int pb) {
    const int jt0 = col0 + t * 64;
    #pragma unroll
    for (int i = 0; i < 2; ++i) {
      const int s   = i * 256 + tid;
      const int col = s >> 3;
      const int cf  = (s & 7) ^ (col & 7);
      const u8* g = reps8 + (size_t)(jt0 + col) * DP + cf * 16;
      __builtin_amdgcn_global_load_lds(
          (const AS1 void*)g,
          (AS3 void*)(Bs[pb] + (size_t)(i * 256 + wave * 64) * 16), 16, 0, 0);
    }
  };

  stage(0, 0);
  for (int t = 0; t < 2; ++t) {
    __syncthreads();
    if (t == 0) stage(1, 1);
    const u8* buf = Bs[t & 1];

    #pragma unroll
    for (int g = 0; g < 2; ++g) {
      f32x4 pacc[2][4];
      __builtin_amdgcn_s_setprio(1);
      #pragma unroll
      for (int h = 0; h < 2; ++h) {
        const int st = g * 2 + h;
        const int coln = st * 16 + l15;
        const u8* cbase = buf + (size_t)coln * DP;
        const int c0 = ((2 * quad)     ^ (coln & 7)) * 16;
        const int c1 = ((2 * quad + 1) ^ (coln & 7)) * 16;
        uint4 b0 = *(const uint4*)(cbase + c0);
        uint4 b1 = *(const uint4*)(cbase + c1);
        i32x8 bf = (i32x8){(int)b0.x, (int)b0.y, (int)b0.z, (int)b0.w,
                           (int)b1.x, (int)b1.y, (int)b1.z, (int)b1.w};
        #pragma unroll
        for (int c = 0; c < 4; ++c) {
          pacc[h][c] = __builtin_amdgcn_mfma_scale_f32_16x16x128_f8f6f4(
              af[c], bf, (f32x4){0.f, 0.f, 0.f, 0.f}, 0, 0, 0,
              0x7F7F7F7F, 0, 0x7F7F7F7F);
        }
      }
      __builtin_amdgcn_s_setprio(0);

      #pragma unroll
      for (int h = 0; h < 2; ++h) {
        float csp[4] = {0.f, 0.f, 0.f, 0.f};
        #pragma unroll
        for (int c = 0; c < 4; ++c) {
          #pragma unroll
          for (int r = 0; r < 4; ++r) {
            float ev = __builtin_amdgcn_exp2f(pacc[h][c][r] * SCALE_LOG2);
            rs[c][r] += ev;
            csp[r] += ev;
          }
        }
        if (!diag) {
          float cs = (csp[0] + csp[1]) + (csp[2] + csp[3]);
          cs += __shfl_xor(cs, 16);
          cs += __shfl_xor(cs, 32);
          if (quad == 0) csw[wave][t * 64 + (g * 2 + h) * 16 + l15] = cs;
        }
      }
    }
  }

  // row sums -> Spart[row][bxh]
  #pragma unroll
  for (int c = 0; c < 4; ++c) {
    const int i0 = r0 + c * 16 + quad * 4;
    #pragma unroll
    for (int r = 0; r < 4; ++r) {
      float v = rs[c][r];
      v += __shfl_xor(v, 1); v += __shfl_xor(v, 2);
      v += __shfl_xor(v, 4); v += __shfl_xor(v, 8);
      if (l15 == 0) Spart[(size_t)(i0 + r) * NSLICE + bxh] = v;
    }
  }

  // col sums -> Spart[col0+j][2by (+1)]
  if (!diag) {
    __syncthreads();
    if (tid < 128) {
      Spart[(size_t)(col0 + tid) * NSLICE + 2 * by] = csw[0][tid] + csw[1][tid];
    } else {
      const int j = tid - 128;
      Spart[(size_t)(col0 + j) * NSLICE + 2 * by + 1] = csw[2][j] + csw[3][j];
    }
  }
}

// ---------------------------------------------------------------------------
// rowfinal: one wave per row, NO atomics. Spart[row][slice] -> the 64-lane
// read is one coalesced 256 B load (was a 64-cache-line gather).
//   L_i = log(sum(parts) - exp(dii/t) + exp(pos/t)) - pos/t
// ---------------------------------------------------------------------------
__global__ __launch_bounds__(256) void rowfinal_kernel(
    const u8* __restrict__ reps8, const float* __restrict__ Spart,
    float* __restrict__ L) {
  const int tid  = threadIdx.x;
  const int wave = tid >> 6;
  const int lane = tid & 63;
  const int row  = blockIdx.x * 4 + wave;
  const int ua = *(const unsigned short*)(reps8 + (size_t)row * DP + lane * 2);
  const int ub = *(const unsigned short*)(reps8 + (size_t)(row ^ B_ROWS) * DP + lane * 2);
  float a0 = __builtin_amdgcn_cvt_f32_fp8(ua, 0);
  float a1 = __builtin_amdgcn_cvt_f32_fp8(ua, 1);
  float b0 = __builtin_amdgcn_cvt_f32_fp8(ub, 0);
  float b1 = __builtin_amdgcn_cvt_f32_fp8(ub, 1);
  float dii = a0 * a0 + a1 * a1;
  float pos = a0 * b0 + a1 * b1;
  float ps  = Spart[(size_t)row * NSLICE + lane];   // coalesced
  #pragma unroll
  for (int m = 1; m < 64; m <<= 1) {
    dii += __shfl_xor(dii, m);
    pos += __shfl_xor(pos, m);
    ps  += __shfl_xor(ps, m);
  }
  if (lane == 0) {
    float Si = ps - __builtin_amdgcn_exp2f(dii * SCALE_LOG2)
                  + __builtin_amdgcn_exp2f(pos * SCALE_LOG2);
    L[row] = logf(Si) - pos * INV_T;
  }
}

// ---------------------------------------------------------------------------
// reduce: mean over 8192 per-row losses -> d_out[0]. Single block.
// ---------------------------------------------------------------------------
__global__ __launch_bounds__(1024) void reduce_kernel(
    const float* __restrict__ L, float* __restrict__ out) {
  const int tid = threadIdx.x;
  float acc = 0.f;
  for (int i = tid; i < NTOT; i += 1024) acc += L[i];
  #pragma unroll
  for (int m = 1; m < 64; m <<= 1) acc += __shfl_xor(acc, m);
  __shared__ float wsum[16];
  if ((tid & 63) == 0) wsum[tid >> 6] = acc;
  __syncthreads();
  if (tid < 16) {
    float v = wsum[tid];
    #pragma unroll
    for (int m = 1; m < 16; m <<= 1) v += __shfl_xor(v, m);
    if (tid == 0) out[0] = v * (1.0f / NTOT);
  }
}

// ---------------------------------------------------------------------------
extern "C" void kernel_launch(void* const* d_in, const int* in_sizes, int n_in,
                              void* d_out, int out_size, void* d_ws, size_t ws_size,
                              hipStream_t stream) {
  const float* x_img  = (const float*)d_in[0];
  const float* x_txt  = (const float*)d_in[1];
  const float* We_img = (const float*)d_in[2];
  const float* be_img = (const float*)d_in[3];
  const float* We_txt = (const float*)d_in[4];
  const float* be_txt = (const float*)d_in[5];
  const float* W1_img = (const float*)d_in[6];
  const float* b1_img = (const float*)d_in[7];
  const float* W2_img = (const float*)d_in[8];
  const float* b2_img = (const float*)d_in[9];
  const float* W1_txt = (const float*)d_in[10];
  const float* b1_txt = (const float*)d_in[11];
  const float* W2_txt = (const float*)d_in[12];
  const float* b2_txt = (const float*)d_in[13];

  char* p = (char*)d_ws;
  bf16_t* xbf_img = (bf16_t*)p; p += (size_t)B_ROWS * DIN * 2;
  bf16_t* xbf_txt = (bf16_t*)p; p += (size_t)B_ROWS * DIN * 2;
  bf16_t* Wet_img = (bf16_t*)p; p += (size_t)DENC * DIN * 2;
  bf16_t* Wet_txt = (bf16_t*)p; p += (size_t)DENC * DIN * 2;
  bf16_t* W1t_img = (bf16_t*)p; p += (size_t)DH * DENC * 2;
  bf16_t* W1t_txt = (bf16_t*)p; p += (size_t)DH * DENC * 2;
  bf16_t* W2t_img = (bf16_t*)p; p += (size_t)DP * DH * 2;
  bf16_t* W2t_txt = (bf16_t*)p; p += (size_t)DP * DH * 2;
  bf16_t* h_img   = (bf16_t*)p; p += (size_t)B_ROWS * DENC * 2;
  bf16_t* h_txt   = (bf16_t*)p; p += (size_t)B_ROWS * DENC * 2;
  bf16_t* g_img   = (bf16_t*)p; p += (size_t)B_ROWS * DH * 2;
  bf16_t* g_txt   = (bf16_t*)p; p += (size_t)B_ROWS * DH * 2;
  u8*     reps8   = (u8*)    p; p += (size_t)NTOT * DP;
  float*  Spart   = (float*) p; p += (size_t)NTOT * NSLICE * 4;
  float*  L       = (float*) p; p += (size_t)NTOT * 4;

  prep_kernel<<<336 + 2048, 256, 0, stream>>>(
      x_img, x_txt, We_img, We_txt, W1_img, W1_txt, W2_img, W2_txt,
      xbf_img, xbf_txt, Wet_img, Wet_txt, W1t_img, W1t_txt, W2t_img, W2t_txt);

  // encoder: h = x @ We + be   [4096x512], K=1024 (counted-vmcnt pipeline)
  gemm_glds<128, false><<<dim3(DENC / 64, B_ROWS / 128, 2), 256, 0, stream>>>(
      xbf_img, xbf_txt, Wet_img, Wet_txt, be_img, be_txt, h_img, h_txt,
      DENC, DIN);
  // head 1: g = relu(h @ W1 + b1)   [4096x256], K=512
  gemm_glds<64, true><<<dim3(DH / 64, B_ROWS / 64, 2), 256, 0, stream>>>(
      h_img, h_txt, W1t_img, W1t_txt, b1_img, b1_txt, g_img, g_txt,
      DH, DENC);
  // head 2 + normalize fused -> fp8 reps8 directly (stage-once, 1 barrier)
  head2_norm<<<dim3(B_ROWS / 16, 1, 2), 256, 0, stream>>>(
      g_img, g_txt, W2t_img, W2t_txt, b2_img, b2_txt, reps8);

  // sim partials via MX-fp8 K=128 MFMA — 256x128 upper-triangle blocks
  sim_fp8_kernel<<<dim3(1056), 256, 0, stream>>>(reps8, Spart);
  // per-row loss (coalesced Spart[row][slice] read), no atomics
  rowfinal_kernel<<<NTOT / 4, 256, 0, stream>>>(reps8, Spart, L);
  // mean
  reduce_kernel<<<1, 1024, 0, stream>>>(L, (float*)d_out);
}